// Round 6
// baseline (268.119 us; speedup 1.0000x reference)
//
#include <hip/hip_runtime.h>
#include <hip/hip_bf16.h>

#define ALPHA_ 0.2f
#define NEG_ -9e15f

typedef __attribute__((ext_vector_type(8))) short short8;
typedef __attribute__((ext_vector_type(4))) float f32x4;
typedef __hip_bfloat16 bf16;

__device__ __forceinline__ float lrelu(float x) { return x > 0.f ? x : ALPHA_ * x; }
__device__ __forceinline__ float eluf(float x) { return x > 0.f ? x : expf(x) - 1.f; }
__device__ __forceinline__ unsigned short f2bu(float x) {
  bf16 h = __float2bfloat16(x);
  return *reinterpret_cast<unsigned short*>(&h);
}
__device__ __forceinline__ float bu2f(unsigned short u) {
  bf16 h = *reinterpret_cast<bf16*>(&u);
  return __bfloat162float(h);
}
__device__ __forceinline__ void gload_lds16(const void* g, void* l) {
  __builtin_amdgcn_global_load_lds((const __attribute__((address_space(1))) void*)g,
                                   (__attribute__((address_space(3))) void*)l,
                                   16, 0, 0);
}

// ---------------- k_cvtw: all weight transposes+converts in one launch ------
__global__ void k_cvtw(const float* __restrict__ W1, const float* __restrict__ W2,
                       const float* __restrict__ W_out, const float* __restrict__ Wc,
                       unsigned short* __restrict__ W1T, unsigned short* __restrict__ W2T,
                       unsigned short* __restrict__ W_outT, unsigned short* __restrict__ WcT) {
  long id = (long)blockIdx.x * 256 + threadIdx.x;
  if (id < 589824) {  // W1: R=1152 C=512
    int c = (int)(id / 1152), r = (int)(id % 1152);
    W1T[id] = f2bu(W1[(size_t)r * 512 + c]);
    return;
  }
  id -= 589824;
  if (id < 65536) {   // W2: R=512 C=128
    int c = (int)(id / 512), r = (int)(id % 512);
    W2T[id] = f2bu(W2[(size_t)r * 128 + c]);
    return;
  }
  id -= 65536;
  if (id < 32768) {   // W_out: R=256 C=128
    int c = (int)(id / 256), r = (int)(id % 256);
    W_outT[id] = f2bu(W_out[(size_t)r * 128 + c]);
    return;
  }
  id -= 32768;
  if (id < 16384) {   // Wc: R=128 C=128
    int c = (int)(id / 128), r = (int)(id % 128);
    WcT[id] = f2bu(Wc[(size_t)r * 128 + c]);
  }
}

// ---------------- k_gemm1f: hid = relu(prot(f32) @ W1 + b1) -> bf16 ---------
// m97 structure, 128x128 tile, BK=32; A converted f32->bf16 in regs during
// staging (kills the separate cvt pass); B (W1T, NxK) via lds-DMA.
// grid (16384/128)*(512/128) = 512 blocks, 256 thr = 4 waves, LDS 16.4 KB.
__global__ __launch_bounds__(256) void k_gemm1f(
    const float* __restrict__ A, const bf16* __restrict__ Bt,
    const float* __restrict__ bias, bf16* __restrict__ outp) {
  const int K = 1152, N = 512;
  __shared__ bf16 sA[128 * 32];
  __shared__ bf16 sB[128 * 32];
  int t = threadIdx.x;
  int w = t >> 6, lane = t & 63;
  int tm = blockIdx.x >> 2, tn = blockIdx.x & 3;
  int m0 = tm << 7, n0 = tn << 7;
  int r0 = t >> 2, cc = t & 3;
  const float* ga0 = A + (size_t)(m0 + r0) * K + cc * 8;
  const float* ga1 = A + (size_t)(m0 + r0 + 64) * K + cc * 8;
  const bf16* gb0 = Bt + (size_t)(n0 + r0) * K + cc * 8;
  const bf16* gb1 = Bt + (size_t)(n0 + r0 + 64) * K + cc * 8;
  bf16* lb0 = sB + (size_t)t * 8;
  bf16* lb1 = sB + (size_t)(t + 256) * 8;

  int wm = (w >> 1) << 6, wn = (w & 1) << 6;
  int row = lane & 15, quad = lane >> 4;
  f32x4 acc[4][4];
#pragma unroll
  for (int i = 0; i < 4; ++i)
#pragma unroll
    for (int j = 0; j < 4; ++j) acc[i][j] = (f32x4){0.f, 0.f, 0.f, 0.f};

  for (int s = 0; s < 36; ++s) {
    int ko = s << 5;
    __syncthreads();
    gload_lds16(gb0 + ko, lb0);
    gload_lds16(gb1 + ko, lb1);
    float4 a00 = *(const float4*)(ga0 + ko);
    float4 a01 = *(const float4*)(ga0 + ko + 4);
    float4 a10 = *(const float4*)(ga1 + ko);
    float4 a11 = *(const float4*)(ga1 + ko + 4);
    short8 v0, v1;
    v0[0] = (short)f2bu(a00.x); v0[1] = (short)f2bu(a00.y);
    v0[2] = (short)f2bu(a00.z); v0[3] = (short)f2bu(a00.w);
    v0[4] = (short)f2bu(a01.x); v0[5] = (short)f2bu(a01.y);
    v0[6] = (short)f2bu(a01.z); v0[7] = (short)f2bu(a01.w);
    v1[0] = (short)f2bu(a10.x); v1[1] = (short)f2bu(a10.y);
    v1[2] = (short)f2bu(a10.z); v1[3] = (short)f2bu(a10.w);
    v1[4] = (short)f2bu(a11.x); v1[5] = (short)f2bu(a11.y);
    v1[6] = (short)f2bu(a11.z); v1[7] = (short)f2bu(a11.w);
    *(short8*)(sA + (size_t)t * 8) = v0;
    *(short8*)(sA + (size_t)(t + 256) * 8) = v1;
    __syncthreads();
    short8 af[4], bfr[4];
#pragma unroll
    for (int i = 0; i < 4; ++i)
      af[i] = *(const short8*)(sA + (size_t)(wm + i * 16 + row) * 32 + quad * 8);
#pragma unroll
    for (int j = 0; j < 4; ++j)
      bfr[j] = *(const short8*)(sB + (size_t)(wn + j * 16 + row) * 32 + quad * 8);
#pragma unroll
    for (int i = 0; i < 4; ++i)
#pragma unroll
      for (int j = 0; j < 4; ++j)
        acc[i][j] = __builtin_amdgcn_mfma_f32_16x16x32_bf16(af[i], bfr[j], acc[i][j], 0, 0, 0);
  }

  int col = lane & 15;
#pragma unroll
  for (int j = 0; j < 4; ++j) {
    int n = n0 + wn + j * 16 + col;
    float bv = bias[n];
#pragma unroll
    for (int i = 0; i < 4; ++i)
#pragma unroll
      for (int r = 0; r < 4; ++r) {
        int m = m0 + wm + i * 16 + quad * 4 + r;
        float v = acc[i][j][r] + bv;
        outp[(size_t)m * N + n] = __float2bfloat16(v > 0.f ? v : 0.f);
      }
  }
}

// ---------------- k_gemm2: out = lrelu(hid @ W2 + b2) -> f32 amino ----------
// M=16384 K=512 N=128; 64x128 tiles -> 256 blocks (1/CU). 4 waves 2x2,
// each 32x64 via acc[2][4].
__global__ __launch_bounds__(256) void k_gemm2(
    const bf16* __restrict__ A, const bf16* __restrict__ Bt,
    const float* __restrict__ bias, float* __restrict__ out) {
  const int K = 512;
  __shared__ bf16 sA[64 * 32];
  __shared__ bf16 sB[128 * 32];
  int t = threadIdx.x;
  int w = t >> 6, lane = t & 63;
  int m0 = blockIdx.x << 6;
  int r0 = t >> 2, cc = t & 3;
  const bf16* ga0 = A + (size_t)(m0 + r0) * K + cc * 8;
  const bf16* gb0 = Bt + (size_t)r0 * K + cc * 8;
  const bf16* gb1 = Bt + (size_t)(r0 + 64) * K + cc * 8;
  bf16* la0 = sA + (size_t)t * 8;
  bf16* lb0 = sB + (size_t)t * 8;
  bf16* lb1 = sB + (size_t)(t + 256) * 8;
  int wm = (w >> 1) << 5, wn = (w & 1) << 6;
  int row = lane & 15, quad = lane >> 4;
  f32x4 acc[2][4];
#pragma unroll
  for (int i = 0; i < 2; ++i)
#pragma unroll
    for (int j = 0; j < 4; ++j) acc[i][j] = (f32x4){0.f, 0.f, 0.f, 0.f};
  for (int s = 0; s < 16; ++s) {
    int ko = s << 5;
    __syncthreads();
    gload_lds16(ga0 + ko, la0);
    gload_lds16(gb0 + ko, lb0);
    gload_lds16(gb1 + ko, lb1);
    __syncthreads();
    short8 af[2], bfr[4];
#pragma unroll
    for (int i = 0; i < 2; ++i)
      af[i] = *(const short8*)(sA + (size_t)(wm + i * 16 + row) * 32 + quad * 8);
#pragma unroll
    for (int j = 0; j < 4; ++j)
      bfr[j] = *(const short8*)(sB + (size_t)(wn + j * 16 + row) * 32 + quad * 8);
#pragma unroll
    for (int i = 0; i < 2; ++i)
#pragma unroll
      for (int j = 0; j < 4; ++j)
        acc[i][j] = __builtin_amdgcn_mfma_f32_16x16x32_bf16(af[i], bfr[j], acc[i][j], 0, 0, 0);
  }
  int col = lane & 15;
#pragma unroll
  for (int j = 0; j < 4; ++j) {
    int n = wn + j * 16 + col;
    float bv = bias[n];
#pragma unroll
    for (int i = 0; i < 2; ++i)
#pragma unroll
      for (int r = 0; r < 4; ++r) {
        int m = m0 + wm + i * 16 + quad * 4 + r;
        float v = lrelu(acc[i][j][r] + bv);
        int b = m >> 10, l = m & 1023;
        out[((size_t)b * 1536 + 512 + l) * 128 + n] = v;
      }
  }
}

// ---------------- k_tab: per-atom-type Wh table (45 types) ------------------
__global__ __launch_bounds__(256) void k_tab(
    const float* __restrict__ emb_atom, const float* __restrict__ W_gat,
    const float* __restrict__ a_gat, unsigned short* __restrict__ tab_wh,
    float* __restrict__ tab_s1, float* __restrict__ tab_s2) {
  int a = blockIdx.x;
  int t = threadIdx.x;
  __shared__ float av[128];
  __shared__ float whl[256];
  if (t < 128) av[t] = emb_atom[a * 128 + t];
  __syncthreads();
  int h = t >> 6, f = t & 63;
  const float* Wg = W_gat + h * 128 * 64 + f;
  float acc = 0.f;
#pragma unroll 8
  for (int c = 0; c < 128; ++c) acc += av[c] * Wg[c * 64];
  whl[t] = acc;
  tab_wh[a * 256 + t] = f2bu(acc);
  __syncthreads();
  if (t < 8) {
    int hh = t >> 1, which = t & 1;
    float s = 0.f;
    for (int ff = 0; ff < 64; ++ff)
      s += whl[hh * 64 + ff] * a_gat[hh * 128 + which * 64 + ff];
    if (which == 0) tab_s1[a * 4 + hh] = s; else tab_s2[a * 4 + hh] = s;
  }
}

// ---------------- k_gather: WhT[b,h,f,n], s1[b,h,n], s2 ---------------------
__global__ __launch_bounds__(256) void k_gather(
    const int* __restrict__ atoms, const unsigned short* __restrict__ tab_wh,
    const float* __restrict__ tab_s1, const float* __restrict__ tab_s2,
    unsigned short* __restrict__ WhT, float* __restrict__ s1,
    float* __restrict__ s2) {
  int bh = blockIdx.x;
  int b = bh >> 2, h = bh & 3;
  int t = threadIdx.x;
  __shared__ int atom_l[512];
  __shared__ unsigned short tabL[45 * 64];
  atom_l[t] = atoms[b * 512 + t];
  atom_l[t + 256] = atoms[b * 512 + t + 256];
  for (int i = t; i < 45 * 64; i += 256)
    tabL[i] = tab_wh[(i >> 6) * 256 + h * 64 + (i & 63)];
  __syncthreads();
  {
    int n = t;
    s1[(size_t)bh * 512 + n] = tab_s1[atom_l[n] * 4 + h];
    s2[(size_t)bh * 512 + n] = tab_s2[atom_l[n] * 4 + h];
    n = t + 256;
    s1[(size_t)bh * 512 + n] = tab_s1[atom_l[n] * 4 + h];
    s2[(size_t)bh * 512 + n] = tab_s2[atom_l[n] * 4 + h];
  }
  for (int f = 0; f < 64; ++f) {
    WhT[((size_t)bh * 64 + f) * 512 + t] = tabL[atom_l[t] * 64 + f];
    WhT[((size_t)bh * 64 + f) * 512 + t + 256] = tabL[atom_l[t + 256] * 64 + f];
  }
}

// ---------------- k_attn1_mfma: softmax + MFMA att@Wh -> multi (bf16) -------
#define ATTP 520
__global__ __launch_bounds__(256) void k_attn1_mfma(
    const int* __restrict__ adj, const unsigned short* __restrict__ WhT,
    const float* __restrict__ s1, const float* __restrict__ s2,
    unsigned short* __restrict__ multi_bf) {
  int blk = blockIdx.x;
  int rb = blk & 15, h = (blk >> 4) & 3, b = blk >> 6;
  int t = threadIdx.x, w = t >> 6, lane = t & 63;
  __shared__ unsigned short satt[32 * ATTP];
  int n0 = rb * 32;
  size_t bh = ((size_t)b * 4 + h) * 512;

  float s2c[8];
  {
    const float4* sp = (const float4*)(s2 + bh + lane * 8);
    float4 v0 = sp[0], v1 = sp[1];
    s2c[0] = v0.x; s2c[1] = v0.y; s2c[2] = v0.z; s2c[3] = v0.w;
    s2c[4] = v1.x; s2c[5] = v1.y; s2c[6] = v1.z; s2c[7] = v1.w;
  }
  for (int rr = 0; rr < 8; ++rr) {
    int rl = w * 8 + rr;
    int n = n0 + rl;
    float s1v = s1[bh + n];
    const int* ap = adj + (size_t)b * 262144 + (size_t)n * 512 + lane * 8;
    int4 a0 = *(const int4*)ap;
    int4 a1 = *(const int4*)(ap + 4);
    float e[8];
    e[0] = a0.x > 0 ? lrelu(s1v + s2c[0]) : NEG_;
    e[1] = a0.y > 0 ? lrelu(s1v + s2c[1]) : NEG_;
    e[2] = a0.z > 0 ? lrelu(s1v + s2c[2]) : NEG_;
    e[3] = a0.w > 0 ? lrelu(s1v + s2c[3]) : NEG_;
    e[4] = a1.x > 0 ? lrelu(s1v + s2c[4]) : NEG_;
    e[5] = a1.y > 0 ? lrelu(s1v + s2c[5]) : NEG_;
    e[6] = a1.z > 0 ? lrelu(s1v + s2c[6]) : NEG_;
    e[7] = a1.w > 0 ? lrelu(s1v + s2c[7]) : NEG_;
    float mx = e[0];
#pragma unroll
    for (int k = 1; k < 8; ++k) mx = fmaxf(mx, e[k]);
#pragma unroll
    for (int o = 32; o > 0; o >>= 1) mx = fmaxf(mx, __shfl_xor(mx, o));
    float x[8], sm = 0.f;
#pragma unroll
    for (int k = 0; k < 8; ++k) { x[k] = expf(e[k] - mx); sm += x[k]; }
#pragma unroll
    for (int o = 32; o > 0; o >>= 1) sm += __shfl_xor(sm, o);
    float inv = 1.f / sm;
    short8 st;
#pragma unroll
    for (int k = 0; k < 8; ++k) st[k] = (short)f2bu(x[k] * inv);
    *(short8*)(satt + rl * ATTP + lane * 8) = st;
  }
  __syncthreads();

  int row = lane & 15, quad = lane >> 4;
  int f0 = w * 16;
  f32x4 acc0 = {0.f, 0.f, 0.f, 0.f}, acc1 = {0.f, 0.f, 0.f, 0.f};
  const unsigned short* wp = WhT + ((size_t)(b * 4 + h) * 64 + f0 + row) * 512 + quad * 8;
#pragma unroll
  for (int kk = 0; kk < 16; ++kk) {
    short8 bfr = *(const short8*)(wp + kk * 32);
    short8 af0 = *(const short8*)(satt + row * ATTP + kk * 32 + quad * 8);
    short8 af1 = *(const short8*)(satt + (16 + row) * ATTP + kk * 32 + quad * 8);
    acc0 = __builtin_amdgcn_mfma_f32_16x16x32_bf16(af0, bfr, acc0, 0, 0, 0);
    acc1 = __builtin_amdgcn_mfma_f32_16x16x32_bf16(af1, bfr, acc1, 0, 0, 0);
  }
  int col = lane & 15;
#pragma unroll
  for (int r = 0; r < 4; ++r) {
    int f = f0 + col;
    int m = n0 + quad * 4 + r;
    multi_bf[((size_t)b * 512 + m) * 256 + h * 64 + f] = f2bu(eluf(acc0[r]));
    m = n0 + 16 + quad * 4 + r;
    multi_bf[((size_t)b * 512 + m) * 256 + h * 64 + f] = f2bu(eluf(acc1[r]));
  }
}

// ---------------- k_wh2t: Wh2T = (multi @ W_out)^T bf16, + s1b/s2b ----------
#define TP 136
__global__ __launch_bounds__(256) void k_wh2t(
    const bf16* __restrict__ A, const bf16* __restrict__ Bt,
    const float* __restrict__ a_out, unsigned short* __restrict__ Wh2T,
    float* __restrict__ s1b, float* __restrict__ s2b) {
  __shared__ bf16 sA[128 * 32];
  __shared__ bf16 sB[128 * 32];
  __shared__ unsigned short sT[128 * TP];
  __shared__ float sao[256];
  const int K = 256;
  int t = threadIdx.x;
  int w = t >> 6, lane = t & 63;
  int m0 = blockIdx.x << 7;
  sao[t] = a_out[t];
  int r0 = t >> 2, cc = t & 3;
  const bf16* ga0 = A + (size_t)(m0 + r0) * K + cc * 8;
  const bf16* ga1 = A + (size_t)(m0 + r0 + 64) * K + cc * 8;
  const bf16* gb0 = Bt + (size_t)r0 * K + cc * 8;
  const bf16* gb1 = Bt + (size_t)(r0 + 64) * K + cc * 8;
  bf16* la0 = sA + (size_t)t * 8;
  bf16* la1 = sA + (size_t)(t + 256) * 8;
  bf16* lb0 = sB + (size_t)t * 8;
  bf16* lb1 = sB + (size_t)(t + 256) * 8;
  int wm = (w >> 1) << 6, wn = (w & 1) << 6;
  int row = lane & 15, quad = lane >> 4;
  f32x4 acc[4][4];
#pragma unroll
  for (int i = 0; i < 4; ++i)
#pragma unroll
    for (int j = 0; j < 4; ++j) acc[i][j] = (f32x4){0.f, 0.f, 0.f, 0.f};
  for (int s = 0; s < 8; ++s) {
    __syncthreads();
    int ko = s << 5;
    gload_lds16(ga0 + ko, la0);
    gload_lds16(ga1 + ko, la1);
    gload_lds16(gb0 + ko, lb0);
    gload_lds16(gb1 + ko, lb1);
    __syncthreads();
    short8 af[4], bfr[4];
#pragma unroll
    for (int i = 0; i < 4; ++i)
      af[i] = *(const short8*)(sA + (size_t)(wm + i * 16 + row) * 32 + quad * 8);
#pragma unroll
    for (int j = 0; j < 4; ++j)
      bfr[j] = *(const short8*)(sB + (size_t)(wn + j * 16 + row) * 32 + quad * 8);
#pragma unroll
    for (int i = 0; i < 4; ++i)
#pragma unroll
      for (int j = 0; j < 4; ++j)
        acc[i][j] = __builtin_amdgcn_mfma_f32_16x16x32_bf16(af[i], bfr[j], acc[i][j], 0, 0, 0);
  }
  __syncthreads();
  int col = lane & 15;
#pragma unroll
  for (int i = 0; i < 4; ++i)
#pragma unroll
    for (int j = 0; j < 4; ++j)
#pragma unroll
      for (int r = 0; r < 4; ++r)
        sT[(wn + j * 16 + col) * TP + wm + i * 16 + quad * 4 + r] = f2bu(acc[i][j][r]);
  __syncthreads();
  int b = m0 >> 9, mb = m0 & 511;
  {
    int f = t >> 1, half = t & 1;
    const unsigned short* srow = sT + f * TP + half * 64;
    unsigned short* dst = Wh2T + ((size_t)b * 128 + f) * 512 + mb + half * 64;
#pragma unroll
    for (int c = 0; c < 64; c += 8)
      *(short8*)(dst + c) = *(const short8*)(srow + c);
  }
  if (t < 128) {
    float acc1 = 0.f, acc2 = 0.f;
#pragma unroll 4
    for (int f = 0; f < 128; ++f) {
      float v = bu2f(sT[f * TP + t]);
      acc1 += v * sao[f];
      acc2 += v * sao[128 + f];
    }
    s1b[b * 512 + mb + t] = acc1;
    s2b[b * 512 + mb + t] = acc2;
  }
}

// ---------------- k_attn2_mfma: softmax + att@Wh2 -> elu -> @Wc -> out ------
__global__ __launch_bounds__(256) void k_attn2_mfma(
    const int* __restrict__ adj, const unsigned short* __restrict__ Wh2T,
    const float* __restrict__ s1b, const float* __restrict__ s2b,
    const unsigned short* __restrict__ WcT, const float* __restrict__ bc,
    float* __restrict__ out) {
  int blk = blockIdx.x;
  int rb = blk & 15, b = blk >> 4;
  int t = threadIdx.x, w = t >> 6, lane = t & 63;
  __shared__ unsigned short satt[32 * ATTP];
  __shared__ unsigned short sorow[32 * TP];
  int n0 = rb * 32;
  size_t bb = (size_t)b * 512;

  float s2c[8];
  {
    const float4* sp = (const float4*)(s2b + bb + lane * 8);
    float4 v0 = sp[0], v1 = sp[1];
    s2c[0] = v0.x; s2c[1] = v0.y; s2c[2] = v0.z; s2c[3] = v0.w;
    s2c[4] = v1.x; s2c[5] = v1.y; s2c[6] = v1.z; s2c[7] = v1.w;
  }
  for (int rr = 0; rr < 8; ++rr) {
    int rl = w * 8 + rr;
    int n = n0 + rl;
    float s1v = s1b[bb + n];
    const int* ap = adj + (size_t)b * 262144 + (size_t)n * 512 + lane * 8;
    int4 a0 = *(const int4*)ap;
    int4 a1 = *(const int4*)(ap + 4);
    float e[8];
    e[0] = a0.x > 0 ? lrelu(s1v + s2c[0]) : NEG_;
    e[1] = a0.y > 0 ? lrelu(s1v + s2c[1]) : NEG_;
    e[2] = a0.z > 0 ? lrelu(s1v + s2c[2]) : NEG_;
    e[3] = a0.w > 0 ? lrelu(s1v + s2c[3]) : NEG_;
    e[4] = a1.x > 0 ? lrelu(s1v + s2c[4]) : NEG_;
    e[5] = a1.y > 0 ? lrelu(s1v + s2c[5]) : NEG_;
    e[6] = a1.z > 0 ? lrelu(s1v + s2c[6]) : NEG_;
    e[7] = a1.w > 0 ? lrelu(s1v + s2c[7]) : NEG_;
    float mx = e[0];
#pragma unroll
    for (int k = 1; k < 8; ++k) mx = fmaxf(mx, e[k]);
#pragma unroll
    for (int o = 32; o > 0; o >>= 1) mx = fmaxf(mx, __shfl_xor(mx, o));
    float x[8], sm = 0.f;
#pragma unroll
    for (int k = 0; k < 8; ++k) { x[k] = expf(e[k] - mx); sm += x[k]; }
#pragma unroll
    for (int o = 32; o > 0; o >>= 1) sm += __shfl_xor(sm, o);
    float inv = 1.f / sm;
    short8 st;
#pragma unroll
    for (int k = 0; k < 8; ++k) st[k] = (short)f2bu(x[k] * inv);
    *(short8*)(satt + rl * ATTP + lane * 8) = st;
  }
  __syncthreads();

  int row = lane & 15, quad = lane >> 4, col = lane & 15;
  f32x4 acc[2][2];
  acc[0][0] = (f32x4){0.f, 0.f, 0.f, 0.f}; acc[0][1] = acc[0][0];
  acc[1][0] = acc[0][0]; acc[1][1] = acc[0][0];
  int f0a = w * 16, f0b = (w + 4) * 16;
  const unsigned short* wpa = Wh2T + ((size_t)b * 128 + f0a + row) * 512 + quad * 8;
  const unsigned short* wpb = Wh2T + ((size_t)b * 128 + f0b + row) * 512 + quad * 8;
#pragma unroll
  for (int kk = 0; kk < 16; ++kk) {
    short8 ba = *(const short8*)(wpa + kk * 32);
    short8 bb2 = *(const short8*)(wpb + kk * 32);
    short8 af0 = *(const short8*)(satt + row * ATTP + kk * 32 + quad * 8);
    short8 af1 = *(const short8*)(satt + (16 + row) * ATTP + kk * 32 + quad * 8);
    acc[0][0] = __builtin_amdgcn_mfma_f32_16x16x32_bf16(af0, ba, acc[0][0], 0, 0, 0);
    acc[0][1] = __builtin_amdgcn_mfma_f32_16x16x32_bf16(af0, bb2, acc[0][1], 0, 0, 0);
    acc[1][0] = __builtin_amdgcn_mfma_f32_16x16x32_bf16(af1, ba, acc[1][0], 0, 0, 0);
    acc[1][1] = __builtin_amdgcn_mfma_f32_16x16x32_bf16(af1, bb2, acc[1][1], 0, 0, 0);
  }
#pragma unroll
  for (int rg = 0; rg < 2; ++rg)
#pragma unroll
    for (int jb = 0; jb < 2; ++jb) {
      int f0 = (w + jb * 4) * 16;
#pragma unroll
      for (int r = 0; r < 4; ++r)
        sorow[(rg * 16 + quad * 4 + r) * TP + f0 + col] = f2bu(eluf(acc[rg][jb][r]));
    }
  __syncthreads();

  f32x4 c2[2][2];
  c2[0][0] = (f32x4){0.f, 0.f, 0.f, 0.f}; c2[0][1] = c2[0][0];
  c2[1][0] = c2[0][0]; c2[1][1] = c2[0][0];
  const unsigned short* wca = WcT + (size_t)(f0a + row) * 128 + quad * 8;
  const unsigned short* wcb = WcT + (size_t)(f0b + row) * 128 + quad * 8;
#pragma unroll
  for (int kk = 0; kk < 4; ++kk) {
    short8 ba = *(const short8*)(wca + kk * 32);
    short8 bb2 = *(const short8*)(wcb + kk * 32);
    short8 af0 = *(const short8*)(sorow + row * TP + kk * 32 + quad * 8);
    short8 af1 = *(const short8*)(sorow + (16 + row) * TP + kk * 32 + quad * 8);
    c2[0][0] = __builtin_amdgcn_mfma_f32_16x16x32_bf16(af0, ba, c2[0][0], 0, 0, 0);
    c2[0][1] = __builtin_amdgcn_mfma_f32_16x16x32_bf16(af0, bb2, c2[0][1], 0, 0, 0);
    c2[1][0] = __builtin_amdgcn_mfma_f32_16x16x32_bf16(af1, ba, c2[1][0], 0, 0, 0);
    c2[1][1] = __builtin_amdgcn_mfma_f32_16x16x32_bf16(af1, bb2, c2[1][1], 0, 0, 0);
  }
#pragma unroll
  for (int rg = 0; rg < 2; ++rg)
#pragma unroll
    for (int jb = 0; jb < 2; ++jb) {
      int c = (w + jb * 4) * 16 + col;
      float bcv = bc[c];
#pragma unroll
      for (int r = 0; r < 4; ++r) {
        int n = n0 + rg * 16 + quad * 4 + r;
        out[((size_t)b * 1536 + n) * 128 + c] = lrelu(c2[rg][jb][r] + bcv);
      }
    }
}

extern "C" void kernel_launch(void* const* d_in, const int* in_sizes, int n_in,
                              void* d_out, int out_size, void* d_ws, size_t ws_size,
                              hipStream_t stream) {
  const int* atoms = (const int*)d_in[0];
  const int* adj = (const int*)d_in[1];
  const float* prot = (const float*)d_in[3];
  const float* emb_atom = (const float*)d_in[5];
  const float* W_gat = (const float*)d_in[6];
  const float* a_gat = (const float*)d_in[7];
  const float* W_out = (const float*)d_in[8];
  const float* a_out = (const float*)d_in[9];
  const float* Wc = (const float*)d_in[10];
  const float* bc = (const float*)d_in[11];
  const float* W1 = (const float*)d_in[12];
  const float* b1 = (const float*)d_in[13];
  const float* W2 = (const float*)d_in[14];
  const float* b2 = (const float*)d_in[15];
  float* out = (float*)d_out;

  char* p = (char*)d_ws;
  unsigned short* W1T = (unsigned short*)p;      p += (size_t)512 * 1152 * 2;
  unsigned short* W2T = (unsigned short*)p;      p += (size_t)128 * 512 * 2;
  unsigned short* W_outT = (unsigned short*)p;   p += (size_t)128 * 256 * 2;
  unsigned short* WcT = (unsigned short*)p;      p += (size_t)128 * 128 * 2;
  bf16* hidp = (bf16*)p;                         p += (size_t)16384 * 512 * 2;
  unsigned short* WhT = (unsigned short*)p;      p += (size_t)64 * 64 * 512 * 2;
  unsigned short* multi_bf = (unsigned short*)p; p += (size_t)16 * 512 * 256 * 2;
  unsigned short* Wh2T = (unsigned short*)p;     p += (size_t)16 * 128 * 512 * 2;
  float* s1 = (float*)p;          p += 64 * 512 * 4;
  float* s2 = (float*)p;          p += 64 * 512 * 4;
  float* s1b = (float*)p;         p += 16 * 512 * 4;
  float* s2b = (float*)p;         p += 16 * 512 * 4;
  unsigned short* tab_wh = (unsigned short*)p;   p += 64 * 1024;
  float* tab_s1 = (float*)p;      p += 4096;
  float* tab_s2 = (float*)p;      p += 4096;

  k_cvtw<<<2752, 256, 0, stream>>>(W1, W2, W_out, Wc, W1T, W2T, W_outT, WcT);
  k_gemm1f<<<512, 256, 0, stream>>>(prot, (const bf16*)W1T, b1, hidp);
  k_gemm2<<<256, 256, 0, stream>>>(hidp, (const bf16*)W2T, b2, out);

  k_tab<<<45, 256, 0, stream>>>(emb_atom, W_gat, a_gat, tab_wh, tab_s1, tab_s2);
  k_gather<<<64, 256, 0, stream>>>(atoms, tab_wh, tab_s1, tab_s2, WhT, s1, s2);
  k_attn1_mfma<<<1024, 256, 0, stream>>>(adj, WhT, s1, s2, multi_bf);
  k_wh2t<<<64, 256, 0, stream>>>((const bf16*)multi_bf, (const bf16*)W_outT, a_out, Wh2T, s1b, s2b);
  k_attn2_mfma<<<256, 256, 0, stream>>>(adj, Wh2T, s1b, s2b, WcT, bc, out);

  (void)in_sizes; (void)n_in; (void)out_size; (void)ws_size;
}

// Round 7
// 263.152 us; speedup vs baseline: 1.0189x; 1.0189x over previous
//
#include <hip/hip_runtime.h>
#include <hip/hip_bf16.h>

#define ALPHA_ 0.2f
#define NEG_ -9e15f

typedef __attribute__((ext_vector_type(8))) short short8;
typedef __attribute__((ext_vector_type(4))) float f32x4;
typedef __hip_bfloat16 bf16;

__device__ __forceinline__ float lrelu(float x) { return x > 0.f ? x : ALPHA_ * x; }
__device__ __forceinline__ float eluf(float x) { return x > 0.f ? x : expf(x) - 1.f; }
__device__ __forceinline__ unsigned short f2bu(float x) {
  bf16 h = __float2bfloat16(x);
  return *reinterpret_cast<unsigned short*>(&h);
}
__device__ __forceinline__ float bu2f(unsigned short u) {
  bf16 h = *reinterpret_cast<bf16*>(&u);
  return __bfloat162float(h);
}
__device__ __forceinline__ void gload_lds16(const void* g, void* l) {
  __builtin_amdgcn_global_load_lds((const __attribute__((address_space(1))) void*)g,
                                   (__attribute__((address_space(3))) void*)l,
                                   16, 0, 0);
}

// ---------------- k_cvtw: all weight transposes+converts in one launch ------
__global__ void k_cvtw(const float* __restrict__ W1, const float* __restrict__ W2,
                       const float* __restrict__ W_out, const float* __restrict__ Wc,
                       unsigned short* __restrict__ W1T, unsigned short* __restrict__ W2T,
                       unsigned short* __restrict__ W_outT, unsigned short* __restrict__ WcT) {
  long id = (long)blockIdx.x * 256 + threadIdx.x;
  if (id < 589824) {  // W1: R=1152 C=512
    int c = (int)(id / 1152), r = (int)(id % 1152);
    W1T[id] = f2bu(W1[(size_t)r * 512 + c]);
    return;
  }
  id -= 589824;
  if (id < 65536) {   // W2: R=512 C=128
    int c = (int)(id / 512), r = (int)(id % 512);
    W2T[id] = f2bu(W2[(size_t)r * 128 + c]);
    return;
  }
  id -= 65536;
  if (id < 32768) {   // W_out: R=256 C=128
    int c = (int)(id / 256), r = (int)(id % 256);
    W_outT[id] = f2bu(W_out[(size_t)r * 128 + c]);
    return;
  }
  id -= 32768;
  if (id < 16384) {   // Wc: R=128 C=128
    int c = (int)(id / 128), r = (int)(id % 128);
    WcT[id] = f2bu(Wc[(size_t)r * 128 + c]);
  }
}

// ---------------- k_gemm1f: hid = relu(prot(f32) @ W1 + b1) -> bf16 ---------
// 128x128 tile, BK=32. A converted f32->bf16 in regs during staging; B via
// lds-DMA. Grid swizzle: tm = bid&127, tn = bid>>7 so the 4 column-tiles
// sharing an A row-strip are 128 apart => same XCD (128%8==0) => A fetched
// from HBM once per strip. sA padded to 40 bf16/row (80B, 16B-aligned) to
// kill ds_write bank conflicts (<=2-way, free).
#define SAP 40
__global__ __launch_bounds__(256) void k_gemm1f(
    const float* __restrict__ A, const bf16* __restrict__ Bt,
    const float* __restrict__ bias, bf16* __restrict__ outp) {
  const int K = 1152, N = 512;
  __shared__ bf16 sA[128 * SAP];
  __shared__ bf16 sB[128 * 32];
  int t = threadIdx.x;
  int w = t >> 6, lane = t & 63;
  int tm = blockIdx.x & 127, tn = blockIdx.x >> 7;
  int m0 = tm << 7, n0 = tn << 7;
  int r0 = t >> 2, cc = t & 3;
  const float* ga0 = A + (size_t)(m0 + r0) * K + cc * 8;
  const float* ga1 = A + (size_t)(m0 + r0 + 64) * K + cc * 8;
  const bf16* gb0 = Bt + (size_t)(n0 + r0) * K + cc * 8;
  const bf16* gb1 = Bt + (size_t)(n0 + r0 + 64) * K + cc * 8;
  bf16* lb0 = sB + (size_t)t * 8;
  bf16* lb1 = sB + (size_t)(t + 256) * 8;

  int wm = (w >> 1) << 6, wn = (w & 1) << 6;
  int row = lane & 15, quad = lane >> 4;
  f32x4 acc[4][4];
#pragma unroll
  for (int i = 0; i < 4; ++i)
#pragma unroll
    for (int j = 0; j < 4; ++j) acc[i][j] = (f32x4){0.f, 0.f, 0.f, 0.f};

  for (int s = 0; s < 36; ++s) {
    int ko = s << 5;
    __syncthreads();
    gload_lds16(gb0 + ko, lb0);
    gload_lds16(gb1 + ko, lb1);
    float4 a00 = *(const float4*)(ga0 + ko);
    float4 a01 = *(const float4*)(ga0 + ko + 4);
    float4 a10 = *(const float4*)(ga1 + ko);
    float4 a11 = *(const float4*)(ga1 + ko + 4);
    short8 v0, v1;
    v0[0] = (short)f2bu(a00.x); v0[1] = (short)f2bu(a00.y);
    v0[2] = (short)f2bu(a00.z); v0[3] = (short)f2bu(a00.w);
    v0[4] = (short)f2bu(a01.x); v0[5] = (short)f2bu(a01.y);
    v0[6] = (short)f2bu(a01.z); v0[7] = (short)f2bu(a01.w);
    v1[0] = (short)f2bu(a10.x); v1[1] = (short)f2bu(a10.y);
    v1[2] = (short)f2bu(a10.z); v1[3] = (short)f2bu(a10.w);
    v1[4] = (short)f2bu(a11.x); v1[5] = (short)f2bu(a11.y);
    v1[6] = (short)f2bu(a11.z); v1[7] = (short)f2bu(a11.w);
    *(short8*)(sA + (size_t)r0 * SAP + cc * 8) = v0;
    *(short8*)(sA + (size_t)(r0 + 64) * SAP + cc * 8) = v1;
    __syncthreads();
    short8 af[4], bfr[4];
#pragma unroll
    for (int i = 0; i < 4; ++i)
      af[i] = *(const short8*)(sA + (size_t)(wm + i * 16 + row) * SAP + quad * 8);
#pragma unroll
    for (int j = 0; j < 4; ++j)
      bfr[j] = *(const short8*)(sB + (size_t)(wn + j * 16 + row) * 32 + quad * 8);
#pragma unroll
    for (int i = 0; i < 4; ++i)
#pragma unroll
      for (int j = 0; j < 4; ++j)
        acc[i][j] = __builtin_amdgcn_mfma_f32_16x16x32_bf16(af[i], bfr[j], acc[i][j], 0, 0, 0);
  }

  int col = lane & 15;
#pragma unroll
  for (int j = 0; j < 4; ++j) {
    int n = n0 + wn + j * 16 + col;
    float bv = bias[n];
#pragma unroll
    for (int i = 0; i < 4; ++i)
#pragma unroll
      for (int r = 0; r < 4; ++r) {
        int m = m0 + wm + i * 16 + quad * 4 + r;
        float v = acc[i][j][r] + bv;
        outp[(size_t)m * N + n] = __float2bfloat16(v > 0.f ? v : 0.f);
      }
  }
}

// ---------------- k_gemm2: out = lrelu(hid @ W2 + b2) -> f32 amino ----------
__global__ __launch_bounds__(256) void k_gemm2(
    const bf16* __restrict__ A, const bf16* __restrict__ Bt,
    const float* __restrict__ bias, float* __restrict__ out) {
  const int K = 512;
  __shared__ bf16 sA[64 * 32];
  __shared__ bf16 sB[128 * 32];
  int t = threadIdx.x;
  int w = t >> 6, lane = t & 63;
  int m0 = blockIdx.x << 6;
  int r0 = t >> 2, cc = t & 3;
  const bf16* ga0 = A + (size_t)(m0 + r0) * K + cc * 8;
  const bf16* gb0 = Bt + (size_t)r0 * K + cc * 8;
  const bf16* gb1 = Bt + (size_t)(r0 + 64) * K + cc * 8;
  bf16* la0 = sA + (size_t)t * 8;
  bf16* lb0 = sB + (size_t)t * 8;
  bf16* lb1 = sB + (size_t)(t + 256) * 8;
  int wm = (w >> 1) << 5, wn = (w & 1) << 6;
  int row = lane & 15, quad = lane >> 4;
  f32x4 acc[2][4];
#pragma unroll
  for (int i = 0; i < 2; ++i)
#pragma unroll
    for (int j = 0; j < 4; ++j) acc[i][j] = (f32x4){0.f, 0.f, 0.f, 0.f};
  for (int s = 0; s < 16; ++s) {
    int ko = s << 5;
    __syncthreads();
    gload_lds16(ga0 + ko, la0);
    gload_lds16(gb0 + ko, lb0);
    gload_lds16(gb1 + ko, lb1);
    __syncthreads();
    short8 af[2], bfr[4];
#pragma unroll
    for (int i = 0; i < 2; ++i)
      af[i] = *(const short8*)(sA + (size_t)(wm + i * 16 + row) * 32 + quad * 8);
#pragma unroll
    for (int j = 0; j < 4; ++j)
      bfr[j] = *(const short8*)(sB + (size_t)(wn + j * 16 + row) * 32 + quad * 8);
#pragma unroll
    for (int i = 0; i < 2; ++i)
#pragma unroll
      for (int j = 0; j < 4; ++j)
        acc[i][j] = __builtin_amdgcn_mfma_f32_16x16x32_bf16(af[i], bfr[j], acc[i][j], 0, 0, 0);
  }
  int col = lane & 15;
#pragma unroll
  for (int j = 0; j < 4; ++j) {
    int n = wn + j * 16 + col;
    float bv = bias[n];
#pragma unroll
    for (int i = 0; i < 2; ++i)
#pragma unroll
      for (int r = 0; r < 4; ++r) {
        int m = m0 + wm + i * 16 + quad * 4 + r;
        float v = lrelu(acc[i][j][r] + bv);
        int b = m >> 10, l = m & 1023;
        out[((size_t)b * 1536 + 512 + l) * 128 + n] = v;
      }
  }
}

// ---------------- k_tab: per-atom-type Wh table (45 types) ------------------
__global__ __launch_bounds__(256) void k_tab(
    const float* __restrict__ emb_atom, const float* __restrict__ W_gat,
    const float* __restrict__ a_gat, unsigned short* __restrict__ tab_wh,
    float* __restrict__ tab_s1, float* __restrict__ tab_s2) {
  int a = blockIdx.x;
  int t = threadIdx.x;
  __shared__ float av[128];
  __shared__ float whl[256];
  if (t < 128) av[t] = emb_atom[a * 128 + t];
  __syncthreads();
  int h = t >> 6, f = t & 63;
  const float* Wg = W_gat + h * 128 * 64 + f;
  float acc = 0.f;
#pragma unroll 8
  for (int c = 0; c < 128; ++c) acc += av[c] * Wg[c * 64];
  whl[t] = acc;
  tab_wh[a * 256 + t] = f2bu(acc);
  __syncthreads();
  if (t < 8) {
    int hh = t >> 1, which = t & 1;
    float s = 0.f;
    for (int ff = 0; ff < 64; ++ff)
      s += whl[hh * 64 + ff] * a_gat[hh * 128 + which * 64 + ff];
    if (which == 0) tab_s1[a * 4 + hh] = s; else tab_s2[a * 4 + hh] = s;
  }
}

// ---------------- k_gather: WhT[b,h,f,n], s1[b,h,n], s2 ---------------------
__global__ __launch_bounds__(256) void k_gather(
    const int* __restrict__ atoms, const unsigned short* __restrict__ tab_wh,
    const float* __restrict__ tab_s1, const float* __restrict__ tab_s2,
    unsigned short* __restrict__ WhT, float* __restrict__ s1,
    float* __restrict__ s2) {
  int bh = blockIdx.x;
  int b = bh >> 2, h = bh & 3;
  int t = threadIdx.x;
  __shared__ int atom_l[512];
  __shared__ unsigned short tabL[45 * 64];
  atom_l[t] = atoms[b * 512 + t];
  atom_l[t + 256] = atoms[b * 512 + t + 256];
  for (int i = t; i < 45 * 64; i += 256)
    tabL[i] = tab_wh[(i >> 6) * 256 + h * 64 + (i & 63)];
  __syncthreads();
  {
    int n = t;
    s1[(size_t)bh * 512 + n] = tab_s1[atom_l[n] * 4 + h];
    s2[(size_t)bh * 512 + n] = tab_s2[atom_l[n] * 4 + h];
    n = t + 256;
    s1[(size_t)bh * 512 + n] = tab_s1[atom_l[n] * 4 + h];
    s2[(size_t)bh * 512 + n] = tab_s2[atom_l[n] * 4 + h];
  }
  for (int f = 0; f < 64; ++f) {
    WhT[((size_t)bh * 64 + f) * 512 + t] = tabL[atom_l[t] * 64 + f];
    WhT[((size_t)bh * 64 + f) * 512 + t + 256] = tabL[atom_l[t + 256] * 64 + f];
  }
}

// ---------------- k_attn1_mfma: softmax + MFMA att@Wh -> multi (bf16) -------
#define ATTP 520
__global__ __launch_bounds__(256) void k_attn1_mfma(
    const int* __restrict__ adj, const unsigned short* __restrict__ WhT,
    const float* __restrict__ s1, const float* __restrict__ s2,
    unsigned short* __restrict__ multi_bf) {
  int blk = blockIdx.x;
  int rb = blk & 15, h = (blk >> 4) & 3, b = blk >> 6;
  int t = threadIdx.x, w = t >> 6, lane = t & 63;
  __shared__ unsigned short satt[32 * ATTP];
  int n0 = rb * 32;
  size_t bh = ((size_t)b * 4 + h) * 512;

  float s2c[8];
  {
    const float4* sp = (const float4*)(s2 + bh + lane * 8);
    float4 v0 = sp[0], v1 = sp[1];
    s2c[0] = v0.x; s2c[1] = v0.y; s2c[2] = v0.z; s2c[3] = v0.w;
    s2c[4] = v1.x; s2c[5] = v1.y; s2c[6] = v1.z; s2c[7] = v1.w;
  }
  for (int rr = 0; rr < 8; ++rr) {
    int rl = w * 8 + rr;
    int n = n0 + rl;
    float s1v = s1[bh + n];
    const int* ap = adj + (size_t)b * 262144 + (size_t)n * 512 + lane * 8;
    int4 a0 = *(const int4*)ap;
    int4 a1 = *(const int4*)(ap + 4);
    float e[8];
    e[0] = a0.x > 0 ? lrelu(s1v + s2c[0]) : NEG_;
    e[1] = a0.y > 0 ? lrelu(s1v + s2c[1]) : NEG_;
    e[2] = a0.z > 0 ? lrelu(s1v + s2c[2]) : NEG_;
    e[3] = a0.w > 0 ? lrelu(s1v + s2c[3]) : NEG_;
    e[4] = a1.x > 0 ? lrelu(s1v + s2c[4]) : NEG_;
    e[5] = a1.y > 0 ? lrelu(s1v + s2c[5]) : NEG_;
    e[6] = a1.z > 0 ? lrelu(s1v + s2c[6]) : NEG_;
    e[7] = a1.w > 0 ? lrelu(s1v + s2c[7]) : NEG_;
    float mx = e[0];
#pragma unroll
    for (int k = 1; k < 8; ++k) mx = fmaxf(mx, e[k]);
#pragma unroll
    for (int o = 32; o > 0; o >>= 1) mx = fmaxf(mx, __shfl_xor(mx, o));
    float x[8], sm = 0.f;
#pragma unroll
    for (int k = 0; k < 8; ++k) { x[k] = expf(e[k] - mx); sm += x[k]; }
#pragma unroll
    for (int o = 32; o > 0; o >>= 1) sm += __shfl_xor(sm, o);
    float inv = 1.f / sm;
    short8 st;
#pragma unroll
    for (int k = 0; k < 8; ++k) st[k] = (short)f2bu(x[k] * inv);
    *(short8*)(satt + rl * ATTP + lane * 8) = st;
  }
  __syncthreads();

  int row = lane & 15, quad = lane >> 4;
  int f0 = w * 16;
  f32x4 acc0 = {0.f, 0.f, 0.f, 0.f}, acc1 = {0.f, 0.f, 0.f, 0.f};
  const unsigned short* wp = WhT + ((size_t)(b * 4 + h) * 64 + f0 + row) * 512 + quad * 8;
#pragma unroll
  for (int kk = 0; kk < 16; ++kk) {
    short8 bfr = *(const short8*)(wp + kk * 32);
    short8 af0 = *(const short8*)(satt + row * ATTP + kk * 32 + quad * 8);
    short8 af1 = *(const short8*)(satt + (16 + row) * ATTP + kk * 32 + quad * 8);
    acc0 = __builtin_amdgcn_mfma_f32_16x16x32_bf16(af0, bfr, acc0, 0, 0, 0);
    acc1 = __builtin_amdgcn_mfma_f32_16x16x32_bf16(af1, bfr, acc1, 0, 0, 0);
  }
  int col = lane & 15;
#pragma unroll
  for (int r = 0; r < 4; ++r) {
    int f = f0 + col;
    int m = n0 + quad * 4 + r;
    multi_bf[((size_t)b * 512 + m) * 256 + h * 64 + f] = f2bu(eluf(acc0[r]));
    m = n0 + 16 + quad * 4 + r;
    multi_bf[((size_t)b * 512 + m) * 256 + h * 64 + f] = f2bu(eluf(acc1[r]));
  }
}

// ---------------- k_wh2t: Wh2T = (multi @ W_out)^T bf16, + s1b/s2b ----------
#define TP 136
__global__ __launch_bounds__(256) void k_wh2t(
    const bf16* __restrict__ A, const bf16* __restrict__ Bt,
    const float* __restrict__ a_out, unsigned short* __restrict__ Wh2T,
    float* __restrict__ s1b, float* __restrict__ s2b) {
  __shared__ bf16 sA[128 * 32];
  __shared__ bf16 sB[128 * 32];
  __shared__ unsigned short sT[128 * TP];
  __shared__ float sao[256];
  const int K = 256;
  int t = threadIdx.x;
  int w = t >> 6, lane = t & 63;
  int m0 = blockIdx.x << 7;
  sao[t] = a_out[t];
  int r0 = t >> 2, cc = t & 3;
  const bf16* ga0 = A + (size_t)(m0 + r0) * K + cc * 8;
  const bf16* ga1 = A + (size_t)(m0 + r0 + 64) * K + cc * 8;
  const bf16* gb0 = Bt + (size_t)r0 * K + cc * 8;
  const bf16* gb1 = Bt + (size_t)(r0 + 64) * K + cc * 8;
  bf16* la0 = sA + (size_t)t * 8;
  bf16* la1 = sA + (size_t)(t + 256) * 8;
  bf16* lb0 = sB + (size_t)t * 8;
  bf16* lb1 = sB + (size_t)(t + 256) * 8;
  int wm = (w >> 1) << 6, wn = (w & 1) << 6;
  int row = lane & 15, quad = lane >> 4;
  f32x4 acc[4][4];
#pragma unroll
  for (int i = 0; i < 4; ++i)
#pragma unroll
    for (int j = 0; j < 4; ++j) acc[i][j] = (f32x4){0.f, 0.f, 0.f, 0.f};
  for (int s = 0; s < 8; ++s) {
    __syncthreads();
    int ko = s << 5;
    gload_lds16(ga0 + ko, la0);
    gload_lds16(ga1 + ko, la1);
    gload_lds16(gb0 + ko, lb0);
    gload_lds16(gb1 + ko, lb1);
    __syncthreads();
    short8 af[4], bfr[4];
#pragma unroll
    for (int i = 0; i < 4; ++i)
      af[i] = *(const short8*)(sA + (size_t)(wm + i * 16 + row) * 32 + quad * 8);
#pragma unroll
    for (int j = 0; j < 4; ++j)
      bfr[j] = *(const short8*)(sB + (size_t)(wn + j * 16 + row) * 32 + quad * 8);
#pragma unroll
    for (int i = 0; i < 4; ++i)
#pragma unroll
      for (int j = 0; j < 4; ++j)
        acc[i][j] = __builtin_amdgcn_mfma_f32_16x16x32_bf16(af[i], bfr[j], acc[i][j], 0, 0, 0);
  }
  __syncthreads();
  int col = lane & 15;
#pragma unroll
  for (int i = 0; i < 4; ++i)
#pragma unroll
    for (int j = 0; j < 4; ++j)
#pragma unroll
      for (int r = 0; r < 4; ++r)
        sT[(wn + j * 16 + col) * TP + wm + i * 16 + quad * 4 + r] = f2bu(acc[i][j][r]);
  __syncthreads();
  int b = m0 >> 9, mb = m0 & 511;
  {
    int f = t >> 1, half = t & 1;
    const unsigned short* srow = sT + f * TP + half * 64;
    unsigned short* dst = Wh2T + ((size_t)b * 128 + f) * 512 + mb + half * 64;
#pragma unroll
    for (int c = 0; c < 64; c += 8)
      *(short8*)(dst + c) = *(const short8*)(srow + c);
  }
  if (t < 128) {
    float acc1 = 0.f, acc2 = 0.f;
#pragma unroll 4
    for (int f = 0; f < 128; ++f) {
      float v = bu2f(sT[f * TP + t]);
      acc1 += v * sao[f];
      acc2 += v * sao[128 + f];
    }
    s1b[b * 512 + mb + t] = acc1;
    s2b[b * 512 + mb + t] = acc2;
  }
}

// ---------------- k_attn2_mfma: softmax + att@Wh2 -> elu -> @Wc -> out ------
__global__ __launch_bounds__(256) void k_attn2_mfma(
    const int* __restrict__ adj, const unsigned short* __restrict__ Wh2T,
    const float* __restrict__ s1b, const float* __restrict__ s2b,
    const unsigned short* __restrict__ WcT, const float* __restrict__ bc,
    float* __restrict__ out) {
  int blk = blockIdx.x;
  int rb = blk & 15, b = blk >> 4;
  int t = threadIdx.x, w = t >> 6, lane = t & 63;
  __shared__ unsigned short satt[32 * ATTP];
  __shared__ unsigned short sorow[32 * TP];
  int n0 = rb * 32;
  size_t bb = (size_t)b * 512;

  float s2c[8];
  {
    const float4* sp = (const float4*)(s2b + bb + lane * 8);
    float4 v0 = sp[0], v1 = sp[1];
    s2c[0] = v0.x; s2c[1] = v0.y; s2c[2] = v0.z; s2c[3] = v0.w;
    s2c[4] = v1.x; s2c[5] = v1.y; s2c[6] = v1.z; s2c[7] = v1.w;
  }
  for (int rr = 0; rr < 8; ++rr) {
    int rl = w * 8 + rr;
    int n = n0 + rl;
    float s1v = s1b[bb + n];
    const int* ap = adj + (size_t)b * 262144 + (size_t)n * 512 + lane * 8;
    int4 a0 = *(const int4*)ap;
    int4 a1 = *(const int4*)(ap + 4);
    float e[8];
    e[0] = a0.x > 0 ? lrelu(s1v + s2c[0]) : NEG_;
    e[1] = a0.y > 0 ? lrelu(s1v + s2c[1]) : NEG_;
    e[2] = a0.z > 0 ? lrelu(s1v + s2c[2]) : NEG_;
    e[3] = a0.w > 0 ? lrelu(s1v + s2c[3]) : NEG_;
    e[4] = a1.x > 0 ? lrelu(s1v + s2c[4]) : NEG_;
    e[5] = a1.y > 0 ? lrelu(s1v + s2c[5]) : NEG_;
    e[6] = a1.z > 0 ? lrelu(s1v + s2c[6]) : NEG_;
    e[7] = a1.w > 0 ? lrelu(s1v + s2c[7]) : NEG_;
    float mx = e[0];
#pragma unroll
    for (int k = 1; k < 8; ++k) mx = fmaxf(mx, e[k]);
#pragma unroll
    for (int o = 32; o > 0; o >>= 1) mx = fmaxf(mx, __shfl_xor(mx, o));
    float x[8], sm = 0.f;
#pragma unroll
    for (int k = 0; k < 8; ++k) { x[k] = expf(e[k] - mx); sm += x[k]; }
#pragma unroll
    for (int o = 32; o > 0; o >>= 1) sm += __shfl_xor(sm, o);
    float inv = 1.f / sm;
    short8 st;
#pragma unroll
    for (int k = 0; k < 8; ++k) st[k] = (short)f2bu(x[k] * inv);
    *(short8*)(satt + rl * ATTP + lane * 8) = st;
  }
  __syncthreads();

  int row = lane & 15, quad = lane >> 4, col = lane & 15;
  f32x4 acc[2][2];
  acc[0][0] = (f32x4){0.f, 0.f, 0.f, 0.f}; acc[0][1] = acc[0][0];
  acc[1][0] = acc[0][0]; acc[1][1] = acc[0][0];
  int f0a = w * 16, f0b = (w + 4) * 16;
  const unsigned short* wpa = Wh2T + ((size_t)b * 128 + f0a + row) * 512 + quad * 8;
  const unsigned short* wpb = Wh2T + ((size_t)b * 128 + f0b + row) * 512 + quad * 8;
#pragma unroll
  for (int kk = 0; kk < 16; ++kk) {
    short8 ba = *(const short8*)(wpa + kk * 32);
    short8 bb2 = *(const short8*)(wpb + kk * 32);
    short8 af0 = *(const short8*)(satt + row * ATTP + kk * 32 + quad * 8);
    short8 af1 = *(const short8*)(satt + (16 + row) * ATTP + kk * 32 + quad * 8);
    acc[0][0] = __builtin_amdgcn_mfma_f32_16x16x32_bf16(af0, ba, acc[0][0], 0, 0, 0);
    acc[0][1] = __builtin_amdgcn_mfma_f32_16x16x32_bf16(af0, bb2, acc[0][1], 0, 0, 0);
    acc[1][0] = __builtin_amdgcn_mfma_f32_16x16x32_bf16(af1, ba, acc[1][0], 0, 0, 0);
    acc[1][1] = __builtin_amdgcn_mfma_f32_16x16x32_bf16(af1, bb2, acc[1][1], 0, 0, 0);
  }
#pragma unroll
  for (int rg = 0; rg < 2; ++rg)
#pragma unroll
    for (int jb = 0; jb < 2; ++jb) {
      int f0 = (w + jb * 4) * 16;
#pragma unroll
      for (int r = 0; r < 4; ++r)
        sorow[(rg * 16 + quad * 4 + r) * TP + f0 + col] = f2bu(eluf(acc[rg][jb][r]));
    }
  __syncthreads();

  f32x4 c2[2][2];
  c2[0][0] = (f32x4){0.f, 0.f, 0.f, 0.f}; c2[0][1] = c2[0][0];
  c2[1][0] = c2[0][0]; c2[1][1] = c2[0][0];
  const unsigned short* wca = WcT + (size_t)(f0a + row) * 128 + quad * 8;
  const unsigned short* wcb = WcT + (size_t)(f0b + row) * 128 + quad * 8;
#pragma unroll
  for (int kk = 0; kk < 4; ++kk) {
    short8 ba = *(const short8*)(wca + kk * 32);
    short8 bb2 = *(const short8*)(wcb + kk * 32);
    short8 af0 = *(const short8*)(sorow + row * TP + kk * 32 + quad * 8);
    short8 af1 = *(const short8*)(sorow + (16 + row) * TP + kk * 32 + quad * 8);
    c2[0][0] = __builtin_amdgcn_mfma_f32_16x16x32_bf16(af0, ba, c2[0][0], 0, 0, 0);
    c2[0][1] = __builtin_amdgcn_mfma_f32_16x16x32_bf16(af0, bb2, c2[0][1], 0, 0, 0);
    c2[1][0] = __builtin_amdgcn_mfma_f32_16x16x32_bf16(af1, ba, c2[1][0], 0, 0, 0);
    c2[1][1] = __builtin_amdgcn_mfma_f32_16x16x32_bf16(af1, bb2, c2[1][1], 0, 0, 0);
  }
#pragma unroll
  for (int rg = 0; rg < 2; ++rg)
#pragma unroll
    for (int jb = 0; jb < 2; ++jb) {
      int c = (w + jb * 4) * 16 + col;
      float bcv = bc[c];
#pragma unroll
      for (int r = 0; r < 4; ++r) {
        int n = n0 + rg * 16 + quad * 4 + r;
        out[((size_t)b * 1536 + n) * 128 + c] = lrelu(c2[rg][jb][r] + bcv);
      }
    }
}

extern "C" void kernel_launch(void* const* d_in, const int* in_sizes, int n_in,
                              void* d_out, int out_size, void* d_ws, size_t ws_size,
                              hipStream_t stream) {
  const int* atoms = (const int*)d_in[0];
  const int* adj = (const int*)d_in[1];
  const float* prot = (const float*)d_in[3];
  const float* emb_atom = (const float*)d_in[5];
  const float* W_gat = (const float*)d_in[6];
  const float* a_gat = (const float*)d_in[7];
  const float* W_out = (const float*)d_in[8];
  const float* a_out = (const float*)d_in[9];
  const float* Wc = (const float*)d_in[10];
  const float* bc = (const float*)d_in[11];
  const float* W1 = (const float*)d_in[12];
  const float* b1 = (const float*)d_in[13];
  const float* W2 = (const float*)d_in[14];
  const float* b2 = (const float*)d_in[15];
  float* out = (float*)d_out;

  char* p = (char*)d_ws;
  unsigned short* W1T = (unsigned short*)p;      p += (size_t)512 * 1152 * 2;
  unsigned short* W2T = (unsigned short*)p;      p += (size_t)128 * 512 * 2;
  unsigned short* W_outT = (unsigned short*)p;   p += (size_t)128 * 256 * 2;
  unsigned short* WcT = (unsigned short*)p;      p += (size_t)128 * 128 * 2;
  bf16* hidp = (bf16*)p;                         p += (size_t)16384 * 512 * 2;
  unsigned short* WhT = (unsigned short*)p;      p += (size_t)64 * 64 * 512 * 2;
  unsigned short* multi_bf = (unsigned short*)p; p += (size_t)16 * 512 * 256 * 2;
  unsigned short* Wh2T = (unsigned short*)p;     p += (size_t)16 * 128 * 512 * 2;
  float* s1 = (float*)p;          p += 64 * 512 * 4;
  float* s2 = (float*)p;          p += 64 * 512 * 4;
  float* s1b = (float*)p;         p += 16 * 512 * 4;
  float* s2b = (float*)p;         p += 16 * 512 * 4;
  unsigned short* tab_wh = (unsigned short*)p;   p += 64 * 1024;
  float* tab_s1 = (float*)p;      p += 4096;
  float* tab_s2 = (float*)p;      p += 4096;

  k_cvtw<<<2752, 256, 0, stream>>>(W1, W2, W_out, Wc, W1T, W2T, W_outT, WcT);
  k_gemm1f<<<512, 256, 0, stream>>>(prot, (const bf16*)W1T, b1, hidp);
  k_gemm2<<<256, 256, 0, stream>>>(hidp, (const bf16*)W2T, b2, out);

  k_tab<<<45, 256, 0, stream>>>(emb_atom, W_gat, a_gat, tab_wh, tab_s1, tab_s2);
  k_gather<<<64, 256, 0, stream>>>(atoms, tab_wh, tab_s1, tab_s2, WhT, s1, s2);
  k_attn1_mfma<<<1024, 256, 0, stream>>>(adj, WhT, s1, s2, multi_bf);
  k_wh2t<<<64, 256, 0, stream>>>((const bf16*)multi_bf, (const bf16*)W_outT, a_out, Wh2T, s1b, s2b);
  k_attn2_mfma<<<256, 256, 0, stream>>>(adj, Wh2T, s1b, s2b, WcT, bc, out);

  (void)in_sizes; (void)n_in; (void)out_size; (void)ws_size;
}

// Round 8
// 253.554 us; speedup vs baseline: 1.0574x; 1.0379x over previous
//
#include <hip/hip_runtime.h>
#include <hip/hip_bf16.h>

#define ALPHA_ 0.2f
#define NEG_ -9e15f

typedef __attribute__((ext_vector_type(8))) short short8;
typedef __attribute__((ext_vector_type(4))) float f32x4;
typedef __hip_bfloat16 bf16;

__device__ __forceinline__ float lrelu(float x) { return x > 0.f ? x : ALPHA_ * x; }
__device__ __forceinline__ float eluf(float x) { return x > 0.f ? x : expf(x) - 1.f; }
__device__ __forceinline__ unsigned short f2bu(float x) {
  bf16 h = __float2bfloat16(x);
  return *reinterpret_cast<unsigned short*>(&h);
}
__device__ __forceinline__ float bu2f(unsigned short u) {
  bf16 h = *reinterpret_cast<bf16*>(&u);
  return __bfloat162float(h);
}
__device__ __forceinline__ void gload_lds16(const void* g, void* l) {
  __builtin_amdgcn_global_load_lds((const __attribute__((address_space(1))) void*)g,
                                   (__attribute__((address_space(3))) void*)l,
                                   16, 0, 0);
}

// ---------------- k_cvtw: all weight transposes+converts in one launch ------
__global__ void k_cvtw(const float* __restrict__ W1, const float* __restrict__ W2,
                       const float* __restrict__ W_out, const float* __restrict__ Wc,
                       unsigned short* __restrict__ W1T, unsigned short* __restrict__ W2T,
                       unsigned short* __restrict__ W_outT, unsigned short* __restrict__ WcT) {
  long id = (long)blockIdx.x * 256 + threadIdx.x;
  if (id < 589824) {  // W1: R=1152 C=512
    int c = (int)(id / 1152), r = (int)(id % 1152);
    W1T[id] = f2bu(W1[(size_t)r * 512 + c]);
    return;
  }
  id -= 589824;
  if (id < 65536) {   // W2: R=512 C=128
    int c = (int)(id / 512), r = (int)(id % 512);
    W2T[id] = f2bu(W2[(size_t)r * 128 + c]);
    return;
  }
  id -= 65536;
  if (id < 32768) {   // W_out: R=256 C=128
    int c = (int)(id / 256), r = (int)(id % 256);
    W_outT[id] = f2bu(W_out[(size_t)r * 128 + c]);
    return;
  }
  id -= 32768;
  if (id < 16384) {   // Wc: R=128 C=128
    int c = (int)(id / 128), r = (int)(id % 128);
    WcT[id] = f2bu(Wc[(size_t)r * 128 + c]);
  }
}

// ---------------- k_gemm1f: hid = relu(prot(f32) @ W1 + b1) -> bf16 ---------
// 64x128 tile, BK=32, 1024 blocks (4/CU, 16 waves/CU). Pipelined:
//   sync1 (drains prefetch A-regs + sB DMA for step s)
//   ds_write sA(s) from regs; sync2
//   issue A f32 loads(s+1) + DMA sB(s+1, other buffer)  <- overlap MFMA(s)
//   ds_read frags; 8 MFMA
// XCD swizzle: tm = bid&255, tn = bid>>8 => the 4 column-tiles of an A strip
// are 256 apart => same XCD => A fetched once. sA linear t*16B writes.
__global__ __launch_bounds__(256) void k_gemm1f(
    const float* __restrict__ A, const bf16* __restrict__ Bt,
    const float* __restrict__ bias, bf16* __restrict__ outp) {
  const int K = 1152, N = 512;
  __shared__ bf16 sA[64 * 32];
  __shared__ bf16 sB[2][128 * 32];
  int t = threadIdx.x;
  int w = t >> 6, lane = t & 63;
  int tm = blockIdx.x & 255, tn = blockIdx.x >> 8;
  int m0 = tm << 6, n0 = tn << 7;
  int r0 = t >> 2, cc = t & 3;
  const float* ga = A + (size_t)(m0 + r0) * K + cc * 8;
  const bf16* gb0 = Bt + (size_t)(n0 + r0) * K + cc * 8;
  const bf16* gb1 = Bt + (size_t)(n0 + r0 + 64) * K + cc * 8;

  int wm = (w >> 1) << 5, wn = (w & 1) << 6;
  int row = lane & 15, quad = lane >> 4;
  f32x4 acc[2][4];
#pragma unroll
  for (int i = 0; i < 2; ++i)
#pragma unroll
    for (int j = 0; j < 4; ++j) acc[i][j] = (f32x4){0.f, 0.f, 0.f, 0.f};

  // prologue: prefetch step 0
  float4 p0 = *(const float4*)(ga);
  float4 p1 = *(const float4*)(ga + 4);
  gload_lds16(gb0, sB[0] + (size_t)t * 8);
  gload_lds16(gb1, sB[0] + (size_t)(t + 256) * 8);

  for (int s = 0; s < 36; ++s) {
    int buf = s & 1;
    __syncthreads();  // drains A-regs(s) + sB DMA(s); sA readers(s-1) done
    short8 v;
    v[0] = (short)f2bu(p0.x); v[1] = (short)f2bu(p0.y);
    v[2] = (short)f2bu(p0.z); v[3] = (short)f2bu(p0.w);
    v[4] = (short)f2bu(p1.x); v[5] = (short)f2bu(p1.y);
    v[6] = (short)f2bu(p1.z); v[7] = (short)f2bu(p1.w);
    *(short8*)(sA + (size_t)t * 8) = v;
    __syncthreads();  // sA(s) + sB[buf](s) visible
    if (s + 1 < 36) {
      int ko = (s + 1) << 5;
      p0 = *(const float4*)(ga + ko);
      p1 = *(const float4*)(ga + ko + 4);
      gload_lds16(gb0 + ko, sB[buf ^ 1] + (size_t)t * 8);
      gload_lds16(gb1 + ko, sB[buf ^ 1] + (size_t)(t + 256) * 8);
    }
    short8 af[2], bfr[4];
#pragma unroll
    for (int i = 0; i < 2; ++i)
      af[i] = *(const short8*)(sA + (size_t)(wm + i * 16 + row) * 32 + quad * 8);
#pragma unroll
    for (int j = 0; j < 4; ++j)
      bfr[j] = *(const short8*)(sB[buf] + (size_t)(wn + j * 16 + row) * 32 + quad * 8);
#pragma unroll
    for (int i = 0; i < 2; ++i)
#pragma unroll
      for (int j = 0; j < 4; ++j)
        acc[i][j] = __builtin_amdgcn_mfma_f32_16x16x32_bf16(af[i], bfr[j], acc[i][j], 0, 0, 0);
  }

  int col = lane & 15;
#pragma unroll
  for (int j = 0; j < 4; ++j) {
    int n = n0 + wn + j * 16 + col;
    float bv = bias[n];
#pragma unroll
    for (int i = 0; i < 2; ++i)
#pragma unroll
      for (int r = 0; r < 4; ++r) {
        int m = m0 + wm + i * 16 + quad * 4 + r;
        float v2 = acc[i][j][r] + bv;
        outp[(size_t)m * N + n] = __float2bfloat16(v2 > 0.f ? v2 : 0.f);
      }
  }
}

// ---------------- k_gemm2: out = lrelu(hid @ W2 + b2) -> f32 amino ----------
__global__ __launch_bounds__(256) void k_gemm2(
    const bf16* __restrict__ A, const bf16* __restrict__ Bt,
    const float* __restrict__ bias, float* __restrict__ out) {
  const int K = 512;
  __shared__ bf16 sA[64 * 32];
  __shared__ bf16 sB[128 * 32];
  int t = threadIdx.x;
  int w = t >> 6, lane = t & 63;
  int m0 = blockIdx.x << 6;
  int r0 = t >> 2, cc = t & 3;
  const bf16* ga0 = A + (size_t)(m0 + r0) * K + cc * 8;
  const bf16* gb0 = Bt + (size_t)r0 * K + cc * 8;
  const bf16* gb1 = Bt + (size_t)(r0 + 64) * K + cc * 8;
  bf16* la0 = sA + (size_t)t * 8;
  bf16* lb0 = sB + (size_t)t * 8;
  bf16* lb1 = sB + (size_t)(t + 256) * 8;
  int wm = (w >> 1) << 5, wn = (w & 1) << 6;
  int row = lane & 15, quad = lane >> 4;
  f32x4 acc[2][4];
#pragma unroll
  for (int i = 0; i < 2; ++i)
#pragma unroll
    for (int j = 0; j < 4; ++j) acc[i][j] = (f32x4){0.f, 0.f, 0.f, 0.f};
  for (int s = 0; s < 16; ++s) {
    int ko = s << 5;
    __syncthreads();
    gload_lds16(ga0 + ko, la0);
    gload_lds16(gb0 + ko, lb0);
    gload_lds16(gb1 + ko, lb1);
    __syncthreads();
    short8 af[2], bfr[4];
#pragma unroll
    for (int i = 0; i < 2; ++i)
      af[i] = *(const short8*)(sA + (size_t)(wm + i * 16 + row) * 32 + quad * 8);
#pragma unroll
    for (int j = 0; j < 4; ++j)
      bfr[j] = *(const short8*)(sB + (size_t)(wn + j * 16 + row) * 32 + quad * 8);
#pragma unroll
    for (int i = 0; i < 2; ++i)
#pragma unroll
      for (int j = 0; j < 4; ++j)
        acc[i][j] = __builtin_amdgcn_mfma_f32_16x16x32_bf16(af[i], bfr[j], acc[i][j], 0, 0, 0);
  }
  int col = lane & 15;
#pragma unroll
  for (int j = 0; j < 4; ++j) {
    int n = wn + j * 16 + col;
    float bv = bias[n];
#pragma unroll
    for (int i = 0; i < 2; ++i)
#pragma unroll
      for (int r = 0; r < 4; ++r) {
        int m = m0 + wm + i * 16 + quad * 4 + r;
        float v = lrelu(acc[i][j][r] + bv);
        int b = m >> 10, l = m & 1023;
        out[((size_t)b * 1536 + 512 + l) * 128 + n] = v;
      }
  }
}

// ---------------- k_tab: per-atom-type Wh table (45 types) ------------------
__global__ __launch_bounds__(256) void k_tab(
    const float* __restrict__ emb_atom, const float* __restrict__ W_gat,
    const float* __restrict__ a_gat, unsigned short* __restrict__ tab_wh,
    float* __restrict__ tab_s1, float* __restrict__ tab_s2) {
  int a = blockIdx.x;
  int t = threadIdx.x;
  __shared__ float av[128];
  __shared__ float whl[256];
  if (t < 128) av[t] = emb_atom[a * 128 + t];
  __syncthreads();
  int h = t >> 6, f = t & 63;
  const float* Wg = W_gat + h * 128 * 64 + f;
  float acc = 0.f;
#pragma unroll 8
  for (int c = 0; c < 128; ++c) acc += av[c] * Wg[c * 64];
  whl[t] = acc;
  tab_wh[a * 256 + t] = f2bu(acc);
  __syncthreads();
  if (t < 8) {
    int hh = t >> 1, which = t & 1;
    float s = 0.f;
    for (int ff = 0; ff < 64; ++ff)
      s += whl[hh * 64 + ff] * a_gat[hh * 128 + which * 64 + ff];
    if (which == 0) tab_s1[a * 4 + hh] = s; else tab_s2[a * 4 + hh] = s;
  }
}

// ---------------- k_gather: WhT[b,h,f,n], s1[b,h,n], s2 ---------------------
__global__ __launch_bounds__(256) void k_gather(
    const int* __restrict__ atoms, const unsigned short* __restrict__ tab_wh,
    const float* __restrict__ tab_s1, const float* __restrict__ tab_s2,
    unsigned short* __restrict__ WhT, float* __restrict__ s1,
    float* __restrict__ s2) {
  int bh = blockIdx.x;
  int b = bh >> 2, h = bh & 3;
  int t = threadIdx.x;
  __shared__ int atom_l[512];
  __shared__ unsigned short tabL[45 * 64];
  atom_l[t] = atoms[b * 512 + t];
  atom_l[t + 256] = atoms[b * 512 + t + 256];
  for (int i = t; i < 45 * 64; i += 256)
    tabL[i] = tab_wh[(i >> 6) * 256 + h * 64 + (i & 63)];
  __syncthreads();
  {
    int n = t;
    s1[(size_t)bh * 512 + n] = tab_s1[atom_l[n] * 4 + h];
    s2[(size_t)bh * 512 + n] = tab_s2[atom_l[n] * 4 + h];
    n = t + 256;
    s1[(size_t)bh * 512 + n] = tab_s1[atom_l[n] * 4 + h];
    s2[(size_t)bh * 512 + n] = tab_s2[atom_l[n] * 4 + h];
  }
  for (int f = 0; f < 64; ++f) {
    WhT[((size_t)bh * 64 + f) * 512 + t] = tabL[atom_l[t] * 64 + f];
    WhT[((size_t)bh * 64 + f) * 512 + t + 256] = tabL[atom_l[t + 256] * 64 + f];
  }
}

// ---------------- k_attn1_mfma: softmax + MFMA att@Wh -> multi (bf16) -------
#define ATTP 520
__global__ __launch_bounds__(256) void k_attn1_mfma(
    const int* __restrict__ adj, const unsigned short* __restrict__ WhT,
    const float* __restrict__ s1, const float* __restrict__ s2,
    unsigned short* __restrict__ multi_bf) {
  int blk = blockIdx.x;
  int rb = blk & 15, h = (blk >> 4) & 3, b = blk >> 6;
  int t = threadIdx.x, w = t >> 6, lane = t & 63;
  __shared__ unsigned short satt[32 * ATTP];
  int n0 = rb * 32;
  size_t bh = ((size_t)b * 4 + h) * 512;

  float s2c[8];
  {
    const float4* sp = (const float4*)(s2 + bh + lane * 8);
    float4 v0 = sp[0], v1 = sp[1];
    s2c[0] = v0.x; s2c[1] = v0.y; s2c[2] = v0.z; s2c[3] = v0.w;
    s2c[4] = v1.x; s2c[5] = v1.y; s2c[6] = v1.z; s2c[7] = v1.w;
  }
  for (int rr = 0; rr < 8; ++rr) {
    int rl = w * 8 + rr;
    int n = n0 + rl;
    float s1v = s1[bh + n];
    const int* ap = adj + (size_t)b * 262144 + (size_t)n * 512 + lane * 8;
    int4 a0 = *(const int4*)ap;
    int4 a1 = *(const int4*)(ap + 4);
    float e[8];
    e[0] = a0.x > 0 ? lrelu(s1v + s2c[0]) : NEG_;
    e[1] = a0.y > 0 ? lrelu(s1v + s2c[1]) : NEG_;
    e[2] = a0.z > 0 ? lrelu(s1v + s2c[2]) : NEG_;
    e[3] = a0.w > 0 ? lrelu(s1v + s2c[3]) : NEG_;
    e[4] = a1.x > 0 ? lrelu(s1v + s2c[4]) : NEG_;
    e[5] = a1.y > 0 ? lrelu(s1v + s2c[5]) : NEG_;
    e[6] = a1.z > 0 ? lrelu(s1v + s2c[6]) : NEG_;
    e[7] = a1.w > 0 ? lrelu(s1v + s2c[7]) : NEG_;
    float mx = e[0];
#pragma unroll
    for (int k = 1; k < 8; ++k) mx = fmaxf(mx, e[k]);
#pragma unroll
    for (int o = 32; o > 0; o >>= 1) mx = fmaxf(mx, __shfl_xor(mx, o));
    float x[8], sm = 0.f;
#pragma unroll
    for (int k = 0; k < 8; ++k) { x[k] = expf(e[k] - mx); sm += x[k]; }
#pragma unroll
    for (int o = 32; o > 0; o >>= 1) sm += __shfl_xor(sm, o);
    float inv = 1.f / sm;
    short8 st;
#pragma unroll
    for (int k = 0; k < 8; ++k) st[k] = (short)f2bu(x[k] * inv);
    *(short8*)(satt + rl * ATTP + lane * 8) = st;
  }
  __syncthreads();

  int row = lane & 15, quad = lane >> 4;
  int f0 = w * 16;
  f32x4 acc0 = {0.f, 0.f, 0.f, 0.f}, acc1 = {0.f, 0.f, 0.f, 0.f};
  const unsigned short* wp = WhT + ((size_t)(b * 4 + h) * 64 + f0 + row) * 512 + quad * 8;
#pragma unroll
  for (int kk = 0; kk < 16; ++kk) {
    short8 bfr = *(const short8*)(wp + kk * 32);
    short8 af0 = *(const short8*)(satt + row * ATTP + kk * 32 + quad * 8);
    short8 af1 = *(const short8*)(satt + (16 + row) * ATTP + kk * 32 + quad * 8);
    acc0 = __builtin_amdgcn_mfma_f32_16x16x32_bf16(af0, bfr, acc0, 0, 0, 0);
    acc1 = __builtin_amdgcn_mfma_f32_16x16x32_bf16(af1, bfr, acc1, 0, 0, 0);
  }
  int col = lane & 15;
#pragma unroll
  for (int r = 0; r < 4; ++r) {
    int f = f0 + col;
    int m = n0 + quad * 4 + r;
    multi_bf[((size_t)b * 512 + m) * 256 + h * 64 + f] = f2bu(eluf(acc0[r]));
    m = n0 + 16 + quad * 4 + r;
    multi_bf[((size_t)b * 512 + m) * 256 + h * 64 + f] = f2bu(eluf(acc1[r]));
  }
}

// ---------------- k_wh2t: Wh2T = (multi @ W_out)^T bf16, + s1b/s2b ----------
#define TP 136
__global__ __launch_bounds__(256) void k_wh2t(
    const bf16* __restrict__ A, const bf16* __restrict__ Bt,
    const float* __restrict__ a_out, unsigned short* __restrict__ Wh2T,
    float* __restrict__ s1b, float* __restrict__ s2b) {
  __shared__ bf16 sA[128 * 32];
  __shared__ bf16 sB[128 * 32];
  __shared__ unsigned short sT[128 * TP];
  __shared__ float sao[256];
  const int K = 256;
  int t = threadIdx.x;
  int w = t >> 6, lane = t & 63;
  int m0 = blockIdx.x << 7;
  sao[t] = a_out[t];
  int r0 = t >> 2, cc = t & 3;
  const bf16* ga0 = A + (size_t)(m0 + r0) * K + cc * 8;
  const bf16* ga1 = A + (size_t)(m0 + r0 + 64) * K + cc * 8;
  const bf16* gb0 = Bt + (size_t)r0 * K + cc * 8;
  const bf16* gb1 = Bt + (size_t)(r0 + 64) * K + cc * 8;
  bf16* la0 = sA + (size_t)t * 8;
  bf16* la1 = sA + (size_t)(t + 256) * 8;
  bf16* lb0 = sB + (size_t)t * 8;
  bf16* lb1 = sB + (size_t)(t + 256) * 8;
  int wm = (w >> 1) << 6, wn = (w & 1) << 6;
  int row = lane & 15, quad = lane >> 4;
  f32x4 acc[4][4];
#pragma unroll
  for (int i = 0; i < 4; ++i)
#pragma unroll
    for (int j = 0; j < 4; ++j) acc[i][j] = (f32x4){0.f, 0.f, 0.f, 0.f};
  for (int s = 0; s < 8; ++s) {
    __syncthreads();
    int ko = s << 5;
    gload_lds16(ga0 + ko, la0);
    gload_lds16(ga1 + ko, la1);
    gload_lds16(gb0 + ko, lb0);
    gload_lds16(gb1 + ko, lb1);
    __syncthreads();
    short8 af[4], bfr[4];
#pragma unroll
    for (int i = 0; i < 4; ++i)
      af[i] = *(const short8*)(sA + (size_t)(wm + i * 16 + row) * 32 + quad * 8);
#pragma unroll
    for (int j = 0; j < 4; ++j)
      bfr[j] = *(const short8*)(sB + (size_t)(wn + j * 16 + row) * 32 + quad * 8);
#pragma unroll
    for (int i = 0; i < 4; ++i)
#pragma unroll
      for (int j = 0; j < 4; ++j)
        acc[i][j] = __builtin_amdgcn_mfma_f32_16x16x32_bf16(af[i], bfr[j], acc[i][j], 0, 0, 0);
  }
  __syncthreads();
  int col = lane & 15;
#pragma unroll
  for (int i = 0; i < 4; ++i)
#pragma unroll
    for (int j = 0; j < 4; ++j)
#pragma unroll
      for (int r = 0; r < 4; ++r)
        sT[(wn + j * 16 + col) * TP + wm + i * 16 + quad * 4 + r] = f2bu(acc[i][j][r]);
  __syncthreads();
  int b = m0 >> 9, mb = m0 & 511;
  {
    int f = t >> 1, half = t & 1;
    const unsigned short* srow = sT + f * TP + half * 64;
    unsigned short* dst = Wh2T + ((size_t)b * 128 + f) * 512 + mb + half * 64;
#pragma unroll
    for (int c = 0; c < 64; c += 8)
      *(short8*)(dst + c) = *(const short8*)(srow + c);
  }
  if (t < 128) {
    float acc1 = 0.f, acc2 = 0.f;
#pragma unroll 4
    for (int f = 0; f < 128; ++f) {
      float v = bu2f(sT[f * TP + t]);
      acc1 += v * sao[f];
      acc2 += v * sao[128 + f];
    }
    s1b[b * 512 + mb + t] = acc1;
    s2b[b * 512 + mb + t] = acc2;
  }
}

// ---------------- k_attn2_mfma: softmax + att@Wh2 -> elu -> @Wc -> out ------
__global__ __launch_bounds__(256) void k_attn2_mfma(
    const int* __restrict__ adj, const unsigned short* __restrict__ Wh2T,
    const float* __restrict__ s1b, const float* __restrict__ s2b,
    const unsigned short* __restrict__ WcT, const float* __restrict__ bc,
    float* __restrict__ out) {
  int blk = blockIdx.x;
  int rb = blk & 15, b = blk >> 4;
  int t = threadIdx.x, w = t >> 6, lane = t & 63;
  __shared__ unsigned short satt[32 * ATTP];
  __shared__ unsigned short sorow[32 * TP];
  int n0 = rb * 32;
  size_t bb = (size_t)b * 512;

  float s2c[8];
  {
    const float4* sp = (const float4*)(s2b + bb + lane * 8);
    float4 v0 = sp[0], v1 = sp[1];
    s2c[0] = v0.x; s2c[1] = v0.y; s2c[2] = v0.z; s2c[3] = v0.w;
    s2c[4] = v1.x; s2c[5] = v1.y; s2c[6] = v1.z; s2c[7] = v1.w;
  }
  for (int rr = 0; rr < 8; ++rr) {
    int rl = w * 8 + rr;
    int n = n0 + rl;
    float s1v = s1b[bb + n];
    const int* ap = adj + (size_t)b * 262144 + (size_t)n * 512 + lane * 8;
    int4 a0 = *(const int4*)ap;
    int4 a1 = *(const int4*)(ap + 4);
    float e[8];
    e[0] = a0.x > 0 ? lrelu(s1v + s2c[0]) : NEG_;
    e[1] = a0.y > 0 ? lrelu(s1v + s2c[1]) : NEG_;
    e[2] = a0.z > 0 ? lrelu(s1v + s2c[2]) : NEG_;
    e[3] = a0.w > 0 ? lrelu(s1v + s2c[3]) : NEG_;
    e[4] = a1.x > 0 ? lrelu(s1v + s2c[4]) : NEG_;
    e[5] = a1.y > 0 ? lrelu(s1v + s2c[5]) : NEG_;
    e[6] = a1.z > 0 ? lrelu(s1v + s2c[6]) : NEG_;
    e[7] = a1.w > 0 ? lrelu(s1v + s2c[7]) : NEG_;
    float mx = e[0];
#pragma unroll
    for (int k = 1; k < 8; ++k) mx = fmaxf(mx, e[k]);
#pragma unroll
    for (int o = 32; o > 0; o >>= 1) mx = fmaxf(mx, __shfl_xor(mx, o));
    float x[8], sm = 0.f;
#pragma unroll
    for (int k = 0; k < 8; ++k) { x[k] = expf(e[k] - mx); sm += x[k]; }
#pragma unroll
    for (int o = 32; o > 0; o >>= 1) sm += __shfl_xor(sm, o);
    float inv = 1.f / sm;
    short8 st;
#pragma unroll
    for (int k = 0; k < 8; ++k) st[k] = (short)f2bu(x[k] * inv);
    *(short8*)(satt + rl * ATTP + lane * 8) = st;
  }
  __syncthreads();

  int row = lane & 15, quad = lane >> 4, col = lane & 15;
  f32x4 acc[2][2];
  acc[0][0] = (f32x4){0.f, 0.f, 0.f, 0.f}; acc[0][1] = acc[0][0];
  acc[1][0] = acc[0][0]; acc[1][1] = acc[0][0];
  int f0a = w * 16, f0b = (w + 4) * 16;
  const unsigned short* wpa = Wh2T + ((size_t)b * 128 + f0a + row) * 512 + quad * 8;
  const unsigned short* wpb = Wh2T + ((size_t)b * 128 + f0b + row) * 512 + quad * 8;
#pragma unroll
  for (int kk = 0; kk < 16; ++kk) {
    short8 ba = *(const short8*)(wpa + kk * 32);
    short8 bb2 = *(const short8*)(wpb + kk * 32);
    short8 af0 = *(const short8*)(satt + row * ATTP + kk * 32 + quad * 8);
    short8 af1 = *(const short8*)(satt + (16 + row) * ATTP + kk * 32 + quad * 8);
    acc[0][0] = __builtin_amdgcn_mfma_f32_16x16x32_bf16(af0, ba, acc[0][0], 0, 0, 0);
    acc[0][1] = __builtin_amdgcn_mfma_f32_16x16x32_bf16(af0, bb2, acc[0][1], 0, 0, 0);
    acc[1][0] = __builtin_amdgcn_mfma_f32_16x16x32_bf16(af1, ba, acc[1][0], 0, 0, 0);
    acc[1][1] = __builtin_amdgcn_mfma_f32_16x16x32_bf16(af1, bb2, acc[1][1], 0, 0, 0);
  }
#pragma unroll
  for (int rg = 0; rg < 2; ++rg)
#pragma unroll
    for (int jb = 0; jb < 2; ++jb) {
      int f0 = (w + jb * 4) * 16;
#pragma unroll
      for (int r = 0; r < 4; ++r)
        sorow[(rg * 16 + quad * 4 + r) * TP + f0 + col] = f2bu(eluf(acc[rg][jb][r]));
    }
  __syncthreads();

  f32x4 c2[2][2];
  c2[0][0] = (f32x4){0.f, 0.f, 0.f, 0.f}; c2[0][1] = c2[0][0];
  c2[1][0] = c2[0][0]; c2[1][1] = c2[0][0];
  const unsigned short* wca = WcT + (size_t)(f0a + row) * 128 + quad * 8;
  const unsigned short* wcb = WcT + (size_t)(f0b + row) * 128 + quad * 8;
#pragma unroll
  for (int kk = 0; kk < 4; ++kk) {
    short8 ba = *(const short8*)(wca + kk * 32);
    short8 bb2 = *(const short8*)(wcb + kk * 32);
    short8 af0 = *(const short8*)(sorow + row * TP + kk * 32 + quad * 8);
    short8 af1 = *(const short8*)(sorow + (16 + row) * TP + kk * 32 + quad * 8);
    c2[0][0] = __builtin_amdgcn_mfma_f32_16x16x32_bf16(af0, ba, c2[0][0], 0, 0, 0);
    c2[0][1] = __builtin_amdgcn_mfma_f32_16x16x32_bf16(af0, bb2, c2[0][1], 0, 0, 0);
    c2[1][0] = __builtin_amdgcn_mfma_f32_16x16x32_bf16(af1, ba, c2[1][0], 0, 0, 0);
    c2[1][1] = __builtin_amdgcn_mfma_f32_16x16x32_bf16(af1, bb2, c2[1][1], 0, 0, 0);
  }
#pragma unroll
  for (int rg = 0; rg < 2; ++rg)
#pragma unroll
    for (int jb = 0; jb < 2; ++jb) {
      int c = (w + jb * 4) * 16 + col;
      float bcv = bc[c];
#pragma unroll
      for (int r = 0; r < 4; ++r) {
        int n = n0 + rg * 16 + quad * 4 + r;
        out[((size_t)b * 1536 + n) * 128 + c] = lrelu(c2[rg][jb][r] + bcv);
      }
    }
}

extern "C" void kernel_launch(void* const* d_in, const int* in_sizes, int n_in,
                              void* d_out, int out_size, void* d_ws, size_t ws_size,
                              hipStream_t stream) {
  const int* atoms = (const int*)d_in[0];
  const int* adj = (const int*)d_in[1];
  const float* prot = (const float*)d_in[3];
  const float* emb_atom = (const float*)d_in[5];
  const float* W_gat = (const float*)d_in[6];
  const float* a_gat = (const float*)d_in[7];
  const float* W_out = (const float*)d_in[8];
  const float* a_out = (const float*)d_in[9];
  const float* Wc = (const float*)d_in[10];
  const float* bc = (const float*)d_in[11];
  const float* W1 = (const float*)d_in[12];
  const float* b1 = (const float*)d_in[13];
  const float* W2 = (const float*)d_in[14];
  const float* b2 = (const float*)d_in[15];
  float* out = (float*)d_out;

  char* p = (char*)d_ws;
  unsigned short* W1T = (unsigned short*)p;      p += (size_t)512 * 1152 * 2;
  unsigned short* W2T = (unsigned short*)p;      p += (size_t)128 * 512 * 2;
  unsigned short* W_outT = (unsigned short*)p;   p += (size_t)128 * 256 * 2;
  unsigned short* WcT = (unsigned short*)p;      p += (size_t)128 * 128 * 2;
  bf16* hidp = (bf16*)p;                         p += (size_t)16384 * 512 * 2;
  unsigned short* WhT = (unsigned short*)p;      p += (size_t)64 * 64 * 512 * 2;
  unsigned short* multi_bf = (unsigned short*)p; p += (size_t)16 * 512 * 256 * 2;
  unsigned short* Wh2T = (unsigned short*)p;     p += (size_t)16 * 128 * 512 * 2;
  float* s1 = (float*)p;          p += 64 * 512 * 4;
  float* s2 = (float*)p;          p += 64 * 512 * 4;
  float* s1b = (float*)p;         p += 16 * 512 * 4;
  float* s2b = (float*)p;         p += 16 * 512 * 4;
  unsigned short* tab_wh = (unsigned short*)p;   p += 64 * 1024;
  float* tab_s1 = (float*)p;      p += 4096;
  float* tab_s2 = (float*)p;      p += 4096;

  k_cvtw<<<2752, 256, 0, stream>>>(W1, W2, W_out, Wc, W1T, W2T, W_outT, WcT);
  k_gemm1f<<<1024, 256, 0, stream>>>(prot, (const bf16*)W1T, b1, hidp);
  k_gemm2<<<256, 256, 0, stream>>>(hidp, (const bf16*)W2T, b2, out);

  k_tab<<<45, 256, 0, stream>>>(emb_atom, W_gat, a_gat, tab_wh, tab_s1, tab_s2);
  k_gather<<<64, 256, 0, stream>>>(atoms, tab_wh, tab_s1, tab_s2, WhT, s1, s2);
  k_attn1_mfma<<<1024, 256, 0, stream>>>(adj, WhT, s1, s2, multi_bf);
  k_wh2t<<<64, 256, 0, stream>>>((const bf16*)multi_bf, (const bf16*)W_outT, a_out, Wh2T, s1b, s2b);
  k_attn2_mfma<<<256, 256, 0, stream>>>(adj, Wh2T, s1b, s2b, WcT, bc, out);

  (void)in_sizes; (void)n_in; (void)out_size; (void)ws_size;
}